// Round 4
// baseline (460.562 us; speedup 1.0000x reference)
//
#include <hip/hip_runtime.h>
#include <hip/hip_bf16.h>
#include <math.h>

#define NA 10000
#define NE 256000
#define FDIM 128
#define F3 384
#define NRBF 20
#define NLAYERS 3
#define NMOLS 100
#define FH 64
#define CUTOFF_F 5.0f
#define EPS_F 1e-8f
#define PI_F 3.14159265358979323846f

typedef __attribute__((ext_vector_type(8))) short bf16x8;
typedef __attribute__((ext_vector_type(4))) float f32x4;

__device__ __forceinline__ float silu_f(float x) { return x / (1.0f + expf(-x)); }

__device__ __forceinline__ unsigned short f2bf(float x) {
  unsigned u = __float_as_uint(x);
  return (unsigned short)((u + 0x7FFFu + ((u >> 16) & 1u)) >> 16);
}
__device__ __forceinline__ float bf2f(unsigned short u) {
  return __uint_as_float(((unsigned)u) << 16);
}

// ---------------- geometry (layer-invariant, per edge) ----------------
__global__ __launch_bounds__(256) void geom_kernel(
    const float* __restrict__ xyz, const int* __restrict__ nbrs,
    float* __restrict__ unitv, float* __restrict__ rbfc, float* __restrict__ fcut) {
  int e = blockIdx.x * 256 + threadIdx.x;
  if (e >= NE) return;
  int i = nbrs[2 * e + 0], j = nbrs[2 * e + 1];
  float rx = xyz[3 * j + 0] - xyz[3 * i + 0];
  float ry = xyz[3 * j + 1] - xyz[3 * i + 1];
  float rz = xyz[3 * j + 2] - xyz[3 * i + 2];
  float d = sqrtf(rx * rx + ry * ry + rz * rz + EPS_F);
  float invd = 1.0f / d;
  unitv[3 * e + 0] = rx * invd;
  unitv[3 * e + 1] = ry * invd;
  unitv[3 * e + 2] = rz * invd;
  float fc = 0.0f;
  if (d < CUTOFF_F) fc = 0.5f * (cosf(PI_F * d / CUTOFF_F) + 1.0f);
  fcut[e] = fc;
  float base = PI_F * d / CUTOFF_F;
  float sc = invd * fc;
#pragma unroll
  for (int k = 0; k < NRBF; k++) rbfc[e * NRBF + k] = sinf((float)(k + 1) * base) * sc;
}

// ---------------- CSR build over idx_i (skip fcut==0 edges) ----------------
__global__ __launch_bounds__(256) void count_kernel(
    const int* __restrict__ nbrs, const float* __restrict__ fcut, int* __restrict__ counts) {
  int e = blockIdx.x * 256 + threadIdx.x;
  if (e >= NE) return;
  if (fcut[e] > 0.0f) atomicAdd(&counts[nbrs[2 * e]], 1);
}

__global__ __launch_bounds__(1024) void scan_kernel(const int* __restrict__ counts,
                                                    int* __restrict__ offs) {
  __shared__ int buf[1024];
  __shared__ int carry_s;
  int t = threadIdx.x;
  if (t == 0) { carry_s = 0; offs[0] = 0; }
  __syncthreads();
  for (int base = 0; base < NA; base += 1024) {
    int idx = base + t;
    int val = (idx < NA) ? counts[idx] : 0;
    buf[t] = val;
    __syncthreads();
    for (int off = 1; off < 1024; off <<= 1) {
      int other = (t >= off) ? buf[t - off] : 0;
      __syncthreads();
      buf[t] += other;
      __syncthreads();
    }
    if (idx < NA) offs[idx + 1] = carry_s + buf[t];
    __syncthreads();
    if (t == 1023) carry_s += buf[1023];
    __syncthreads();
  }
}

__global__ __launch_bounds__(256) void fill_kernel(
    const int* __restrict__ nbrs, const float* __restrict__ fcut,
    const int* __restrict__ offs, int* __restrict__ cursor,
    int* __restrict__ csr_eid, int* __restrict__ csr_j) {
  int e = blockIdx.x * 256 + threadIdx.x;
  if (e >= NE) return;
  if (fcut[e] <= 0.0f) return;
  int i = nbrs[2 * e];
  int pos = offs[i] + atomicAdd(&cursor[i], 1);
  csr_eid[pos] = e;
  csr_j[pos] = nbrs[2 * e + 1];
}

// ---------------- init: s = emb[z], v = 0 ----------------
__global__ __launch_bounds__(256) void init_kernel(
    const float* __restrict__ emb, const int* __restrict__ z,
    float* __restrict__ s, float* __restrict__ vA) {
  int t = blockIdx.x * 256 + threadIdx.x;
  if (t < NA * 3 * FDIM) vA[t] = 0.0f;
  if (t < NA * FDIM) {
    int n = t >> 7, f = t & 127;
    s[t] = emb[z[n] * FDIM + f];
  }
}

// ---------------- weight pack: W[K][N] fp32 -> B-fragment bf16 layout ----------------
__global__ __launch_bounds__(256) void pack_kernel(
    const float* __restrict__ src, unsigned short* __restrict__ dst,
    int K, int N, int layers) {
  int t = blockIdx.x * 256 + threadIdx.x;
  int per = K * N;
  if (t >= per * layers) return;
  int lay = t / per;
  int kn = t - lay * per;
  int k = kn / N, n = kn - k * N;
  unsigned short b = f2bf(src[t]);
  int kb = k >> 5, q = (k >> 3) & 3, j = k & 7, nt = n >> 4, c = n & 15;
  int NT = N >> 4;
  dst[(size_t)lay * per + (((kb * NT + nt) * 64 + (q * 16 + c)) * 8 + j)] = b;
}

// ---------------- message MLP via MFMA: phi(bf16) = silu(s@W1+b1)@W2+b2 ----------------
__global__ __launch_bounds__(256) void msg_mfma_kernel(
    const float* __restrict__ s, const unsigned short* __restrict__ pW1,
    const float* __restrict__ b1, const unsigned short* __restrict__ pW2,
    const float* __restrict__ b2, unsigned short* __restrict__ phi_bf) {
  __shared__ bf16x8 sA[4 * 64];
  __shared__ bf16x8 hA[4 * 64];
  int a0 = blockIdx.x * 16;
  int t = threadIdx.x;
  int lane = t & 63, w = t >> 6;
  {
    int kb = t >> 6, l = t & 63;
    int m = l & 15, q = l >> 4;
    const float* sp = s + (size_t)(a0 + m) * FDIM + kb * 32 + q * 8;
    bf16x8 c;
#pragma unroll
    for (int j = 0; j < 8; j++) c[j] = (short)f2bf(sp[j]);
    sA[kb * 64 + l] = c;
  }
  __syncthreads();
  f32x4 accH[2];
#pragma unroll
  for (int t2 = 0; t2 < 2; t2++)
#pragma unroll
    for (int r = 0; r < 4; r++) accH[t2][r] = 0.0f;
  const bf16x8* W1f = (const bf16x8*)pW1;
#pragma unroll
  for (int kb = 0; kb < 4; kb++) {
    bf16x8 a = sA[kb * 64 + lane];
#pragma unroll
    for (int t2 = 0; t2 < 2; t2++) {
      bf16x8 b = W1f[(kb * 8 + 2 * w + t2) * 64 + lane];
      accH[t2] = __builtin_amdgcn_mfma_f32_16x16x32_bf16(a, b, accH[t2], 0, 0, 0);
    }
  }
  short* hs = (short*)hA;
#pragma unroll
  for (int t2 = 0; t2 < 2; t2++) {
    int n = w * 32 + t2 * 16 + (lane & 15);
    int kb = n >> 5, q = (n >> 3) & 3, j = n & 7;
    float bias = b1[n];
#pragma unroll
    for (int r = 0; r < 4; r++) {
      int m = (lane >> 4) * 4 + r;
      hs[(kb * 64 + q * 16 + m) * 8 + j] = (short)f2bf(silu_f(accH[t2][r] + bias));
    }
  }
  __syncthreads();
  f32x4 accP[6];
#pragma unroll
  for (int t6 = 0; t6 < 6; t6++)
#pragma unroll
    for (int r = 0; r < 4; r++) accP[t6][r] = 0.0f;
  const bf16x8* W2f = (const bf16x8*)pW2;
#pragma unroll
  for (int kb = 0; kb < 4; kb++) {
    bf16x8 a = hA[kb * 64 + lane];
#pragma unroll
    for (int t6 = 0; t6 < 6; t6++) {
      bf16x8 b = W2f[(kb * 24 + 6 * w + t6) * 64 + lane];
      accP[t6] = __builtin_amdgcn_mfma_f32_16x16x32_bf16(a, b, accP[t6], 0, 0, 0);
    }
  }
#pragma unroll
  for (int t6 = 0; t6 < 6; t6++) {
    int n = (6 * w + t6) * 16 + (lane & 15);
    float bias = b2[n];
#pragma unroll
    for (int r = 0; r < 4; r++) {
      int m = (lane >> 4) * 4 + r;
      phi_bf[(size_t)(a0 + m) * F3 + n] = f2bf(accP[t6][r] + bias);
    }
  }
}

// ---------------- edge aggregation: bf16 gathers, 2-edge unroll, no atomics ----------------
__global__ __launch_bounds__(128) void edge_kernel(
    const unsigned short* __restrict__ phi_bf, const float* __restrict__ v_in,
    const unsigned short* __restrict__ vbf_in, float* __restrict__ v_out,
    unsigned short* __restrict__ vbf_out, float* __restrict__ s,
    const float* __restrict__ dW, const float* __restrict__ db,
    const int* __restrict__ offs, const int* __restrict__ csr_eid,
    const int* __restrict__ csr_j, const float* __restrict__ rbfc,
    const float* __restrict__ fcut, const float* __restrict__ unitv) {
  int i = blockIdx.x;
  int f = threadIdx.x;
  float wd0[NRBF], wd1[NRBF], wd2[NRBF];
#pragma unroll
  for (int k = 0; k < NRBF; k++) {
    wd0[k] = dW[k * F3 + f];
    wd1[k] = dW[k * F3 + FDIM + f];
    wd2[k] = dW[k * F3 + 2 * FDIM + f];
  }
  float db0 = db[f], db1 = db[FDIM + f], db2 = db[2 * FDIM + f];
  float acc_s = 0.f, av0 = 0.f, av1 = 0.f, av2 = 0.f;
  int p0 = offs[i], p1 = offs[i + 1];
  int p = p0;
  for (; p + 2 <= p1; p += 2) {
    int e0 = csr_eid[p], e1 = csr_eid[p + 1];
    int j0 = csr_j[p], j1 = csr_j[p + 1];
    float fc0 = fcut[e0], fc1 = fcut[e1];
    float ux0 = unitv[3 * e0 + 0], uy0 = unitv[3 * e0 + 1], uz0 = unitv[3 * e0 + 2];
    float ux1 = unitv[3 * e1 + 0], uy1 = unitv[3 * e1 + 1], uz1 = unitv[3 * e1 + 2];
    const float* rb0 = rbfc + (size_t)e0 * NRBF;
    const float* rb1 = rbfc + (size_t)e1 * NRBF;
    const unsigned short* ph0 = phi_bf + (size_t)j0 * F3;
    const unsigned short* ph1 = phi_bf + (size_t)j1 * F3;
    const unsigned short* vj0 = vbf_in + (size_t)j0 * F3;
    const unsigned short* vj1 = vbf_in + (size_t)j1 * F3;
    float w00 = db0 * fc0, w01 = db1 * fc0, w02 = db2 * fc0;
    float w10 = db0 * fc1, w11 = db1 * fc1, w12 = db2 * fc1;
#pragma unroll
    for (int k = 0; k < NRBF; k++) {
      float r0 = rb0[k], r1 = rb1[k];
      w00 += r0 * wd0[k]; w01 += r0 * wd1[k]; w02 += r0 * wd2[k];
      w10 += r1 * wd0[k]; w11 += r1 * wd1[k]; w12 += r1 * wd2[k];
    }
    float i00 = bf2f(ph0[f]) * w00;
    float i01 = bf2f(ph0[FDIM + f]) * w01;
    float i02 = bf2f(ph0[2 * FDIM + f]) * w02;
    float i10 = bf2f(ph1[f]) * w10;
    float i11 = bf2f(ph1[FDIM + f]) * w11;
    float i12 = bf2f(ph1[2 * FDIM + f]) * w12;
    acc_s += i00 + i10;
    av0 += i01 * bf2f(vj0[f]) + i02 * ux0 + i11 * bf2f(vj1[f]) + i12 * ux1;
    av1 += i01 * bf2f(vj0[FDIM + f]) + i02 * uy0 + i11 * bf2f(vj1[FDIM + f]) + i12 * uy1;
    av2 += i01 * bf2f(vj0[2 * FDIM + f]) + i02 * uz0 + i11 * bf2f(vj1[2 * FDIM + f]) + i12 * uz1;
  }
  if (p < p1) {
    int e0 = csr_eid[p];
    int j0 = csr_j[p];
    float fc0 = fcut[e0];
    float ux0 = unitv[3 * e0 + 0], uy0 = unitv[3 * e0 + 1], uz0 = unitv[3 * e0 + 2];
    const float* rb0 = rbfc + (size_t)e0 * NRBF;
    const unsigned short* ph0 = phi_bf + (size_t)j0 * F3;
    const unsigned short* vj0 = vbf_in + (size_t)j0 * F3;
    float w00 = db0 * fc0, w01 = db1 * fc0, w02 = db2 * fc0;
#pragma unroll
    for (int k = 0; k < NRBF; k++) {
      float r0 = rb0[k];
      w00 += r0 * wd0[k]; w01 += r0 * wd1[k]; w02 += r0 * wd2[k];
    }
    float i00 = bf2f(ph0[f]) * w00;
    float i01 = bf2f(ph0[FDIM + f]) * w01;
    float i02 = bf2f(ph0[2 * FDIM + f]) * w02;
    acc_s += i00;
    av0 += i01 * bf2f(vj0[f]) + i02 * ux0;
    av1 += i01 * bf2f(vj0[FDIM + f]) + i02 * uy0;
    av2 += i01 * bf2f(vj0[2 * FDIM + f]) + i02 * uz0;
  }
  s[(size_t)i * FDIM + f] += acc_s;
  const float* vi = v_in + (size_t)i * 3 * FDIM;
  float* vo = v_out + (size_t)i * 3 * FDIM;
  unsigned short* vbo = vbf_out + (size_t)i * 3 * FDIM;
  float n0 = vi[f] + av0;
  float n1 = vi[FDIM + f] + av1;
  float n2 = vi[2 * FDIM + f] + av2;
  vo[f] = n0; vo[FDIM + f] = n1; vo[2 * FDIM + f] = n2;
  vbo[f] = f2bf(n0); vbo[FDIM + f] = f2bf(n1); vbo[2 * FDIM + f] = f2bf(n2);
}

// ---------------- update block via MFMA (also refreshes bf16 v mirror) ----------------
__global__ __launch_bounds__(256) void upd_mfma_kernel(
    float* __restrict__ s, float* __restrict__ v, unsigned short* __restrict__ vbf,
    const unsigned short* __restrict__ pU, const unsigned short* __restrict__ pV,
    const unsigned short* __restrict__ pW1, const float* __restrict__ b1,
    const unsigned short* __restrict__ pW2, const float* __restrict__ b2) {
  __shared__ bf16x8 vAf[3 * 4 * 64];
  __shared__ bf16x8 catA[8 * 64];
  __shared__ bf16x8 hA[4 * 64];
  int a0 = blockIdx.x * 16;
  int t = threadIdx.x;
  int lane = t & 63, w = t >> 6;
  {
    int l = t & 63, kb = (t >> 6) & 3;
    int m = l & 15, q = l >> 4;
#pragma unroll
    for (int rt = 0; rt < 3; rt++) {
      const float* vp = v + (size_t)(a0 + m) * F3 + rt * FDIM + kb * 32 + q * 8;
      bf16x8 c;
#pragma unroll
      for (int j = 0; j < 8; j++) c[j] = (short)f2bf(vp[j]);
      vAf[(rt * 4 + kb) * 64 + l] = c;
    }
    const float* sp = s + (size_t)(a0 + m) * FDIM + kb * 32 + q * 8;
    bf16x8 c;
#pragma unroll
    for (int j = 0; j < 8; j++) c[j] = (short)f2bf(sp[j]);
    catA[kb * 64 + l] = c;
  }
  __syncthreads();
  f32x4 accU[3][2], accV[3][2];
#pragma unroll
  for (int rt = 0; rt < 3; rt++)
#pragma unroll
    for (int t2 = 0; t2 < 2; t2++)
#pragma unroll
      for (int r = 0; r < 4; r++) { accU[rt][t2][r] = 0.0f; accV[rt][t2][r] = 0.0f; }
  const bf16x8* Uf = (const bf16x8*)pU;
  const bf16x8* Vf = (const bf16x8*)pV;
#pragma unroll
  for (int kb = 0; kb < 4; kb++) {
    bf16x8 bu[2], bv[2];
#pragma unroll
    for (int t2 = 0; t2 < 2; t2++) {
      bu[t2] = Uf[(kb * 8 + 2 * w + t2) * 64 + lane];
      bv[t2] = Vf[(kb * 8 + 2 * w + t2) * 64 + lane];
    }
#pragma unroll
    for (int rt = 0; rt < 3; rt++) {
      bf16x8 a = vAf[(rt * 4 + kb) * 64 + lane];
#pragma unroll
      for (int t2 = 0; t2 < 2; t2++) {
        accU[rt][t2] = __builtin_amdgcn_mfma_f32_16x16x32_bf16(a, bu[t2], accU[rt][t2], 0, 0, 0);
        accV[rt][t2] = __builtin_amdgcn_mfma_f32_16x16x32_bf16(a, bv[t2], accV[rt][t2], 0, 0, 0);
      }
    }
  }
  short* cs = (short*)catA;
#pragma unroll
  for (int t2 = 0; t2 < 2; t2++) {
    int g = w * 32 + t2 * 16 + (lane & 15);
    int k = 128 + g;
    int kb = k >> 5, q = (k >> 3) & 3, j = k & 7;
#pragma unroll
    for (int r = 0; r < 4; r++) {
      int m = (lane >> 4) * 4 + r;
      float x0 = accV[0][t2][r], x1 = accV[1][t2][r], x2 = accV[2][t2][r];
      cs[(kb * 64 + q * 16 + m) * 8 + j] = (short)f2bf(sqrtf(x0 * x0 + x1 * x1 + x2 * x2 + EPS_F));
    }
  }
  __syncthreads();
  f32x4 accH[2];
#pragma unroll
  for (int t2 = 0; t2 < 2; t2++)
#pragma unroll
    for (int r = 0; r < 4; r++) accH[t2][r] = 0.0f;
  const bf16x8* W1f = (const bf16x8*)pW1;
#pragma unroll
  for (int kb = 0; kb < 8; kb++) {
    bf16x8 a = catA[kb * 64 + lane];
#pragma unroll
    for (int t2 = 0; t2 < 2; t2++) {
      bf16x8 b = W1f[(kb * 8 + 2 * w + t2) * 64 + lane];
      accH[t2] = __builtin_amdgcn_mfma_f32_16x16x32_bf16(a, b, accH[t2], 0, 0, 0);
    }
  }
  short* hs = (short*)hA;
#pragma unroll
  for (int t2 = 0; t2 < 2; t2++) {
    int n = w * 32 + t2 * 16 + (lane & 15);
    int kb = n >> 5, q = (n >> 3) & 3, j = n & 7;
    float bias = b1[n];
#pragma unroll
    for (int r = 0; r < 4; r++) {
      int m = (lane >> 4) * 4 + r;
      hs[(kb * 64 + q * 16 + m) * 8 + j] = (short)f2bf(silu_f(accH[t2][r] + bias));
    }
  }
  __syncthreads();
  f32x4 accA[3][2];
#pragma unroll
  for (int c3 = 0; c3 < 3; c3++)
#pragma unroll
    for (int t2 = 0; t2 < 2; t2++)
#pragma unroll
      for (int r = 0; r < 4; r++) accA[c3][t2][r] = 0.0f;
  const bf16x8* W2f = (const bf16x8*)pW2;
#pragma unroll
  for (int kb = 0; kb < 4; kb++) {
    bf16x8 a = hA[kb * 64 + lane];
#pragma unroll
    for (int c3 = 0; c3 < 3; c3++)
#pragma unroll
      for (int t2 = 0; t2 < 2; t2++) {
        bf16x8 b = W2f[(kb * 24 + c3 * 8 + 2 * w + t2) * 64 + lane];
        accA[c3][t2] = __builtin_amdgcn_mfma_f32_16x16x32_bf16(a, b, accA[c3][t2], 0, 0, 0);
      }
  }
#pragma unroll
  for (int t2 = 0; t2 < 2; t2++) {
    int g = w * 32 + t2 * 16 + (lane & 15);
    float bb0 = b2[g], bb1 = b2[FDIM + g], bb2 = b2[2 * FDIM + g];
#pragma unroll
    for (int r = 0; r < 4; r++) {
      int m = (lane >> 4) * 4 + r;
      int n = a0 + m;
      float a0v = accA[0][t2][r] + bb0;
      float a1v = accA[1][t2][r] + bb1;
      float a2v = accA[2][t2][r] + bb2;
      float dot = accU[0][t2][r] * accV[0][t2][r] + accU[1][t2][r] * accV[1][t2][r] +
                  accU[2][t2][r] * accV[2][t2][r];
      s[(size_t)n * FDIM + g] += a1v * dot + a2v;
#pragma unroll
      for (int c = 0; c < 3; c++) {
        size_t ix = (size_t)n * F3 + c * FDIM + g;
        float nv = v[ix] + a0v * accU[c][t2][r];
        v[ix] = nv;
        vbf[ix] = f2bf(nv);
      }
    }
  }
}

// ---------------- readout via MFMA ----------------
__global__ __launch_bounds__(256) void readout_mfma_kernel(
    const float* __restrict__ s, const unsigned short* __restrict__ pW1,
    const float* __restrict__ b1, const float* __restrict__ W2, const float* __restrict__ b2,
    const int* __restrict__ mol_idx, float* __restrict__ out) {
  __shared__ bf16x8 sA[4 * 64];
  __shared__ float red[4][16];
  int a0 = blockIdx.x * 16;
  int t = threadIdx.x;
  int lane = t & 63, w = t >> 6;
  {
    int kb = t >> 6, l = t & 63;
    int m = l & 15, q = l >> 4;
    const float* sp = s + (size_t)(a0 + m) * FDIM + kb * 32 + q * 8;
    bf16x8 c;
#pragma unroll
    for (int j = 0; j < 8; j++) c[j] = (short)f2bf(sp[j]);
    sA[kb * 64 + l] = c;
  }
  __syncthreads();
  f32x4 acc;
#pragma unroll
  for (int r = 0; r < 4; r++) acc[r] = 0.0f;
  const bf16x8* W1f = (const bf16x8*)pW1;
#pragma unroll
  for (int kb = 0; kb < 4; kb++) {
    bf16x8 a = sA[kb * 64 + lane];
    bf16x8 b = W1f[(kb * 4 + w) * 64 + lane];
    acc = __builtin_amdgcn_mfma_f32_16x16x32_bf16(a, b, acc, 0, 0, 0);
  }
  int col = w * 16 + (lane & 15);
  float bias = b1[col], w2v = W2[col];
  float val[4];
#pragma unroll
  for (int r = 0; r < 4; r++) val[r] = silu_f(acc[r] + bias) * w2v;
#pragma unroll
  for (int off = 1; off < 16; off <<= 1)
#pragma unroll
    for (int r = 0; r < 4; r++) val[r] += __shfl_xor(val[r], off, 64);
  if ((lane & 15) == 0) {
#pragma unroll
    for (int r = 0; r < 4; r++) red[w][(lane >> 4) * 4 + r] = val[r];
  }
  __syncthreads();
  if (t < 16) {
    float sum = red[0][t] + red[1][t] + red[2][t] + red[3][t] + b2[0];
    atomicAdd(&out[mol_idx[a0 + t]], sum);
  }
}

extern "C" void kernel_launch(void* const* d_in, const int* in_sizes, int n_in,
                              void* d_out, int out_size, void* d_ws, size_t ws_size,
                              hipStream_t stream) {
  const float* xyz = (const float*)d_in[0];
  const int* z = (const int*)d_in[1];
  const int* nbrs = (const int*)d_in[2];
  const int* mol = (const int*)d_in[3];
  const float* emb = (const float*)d_in[4];
  const float* msgW1 = (const float*)d_in[5];
  const float* msgb1 = (const float*)d_in[6];
  const float* msgW2 = (const float*)d_in[7];
  const float* msgb2 = (const float*)d_in[8];
  const float* distW = (const float*)d_in[9];
  const float* distb = (const float*)d_in[10];
  const float* updU = (const float*)d_in[11];
  const float* updV = (const float*)d_in[12];
  const float* updW1 = (const float*)d_in[13];
  const float* updb1 = (const float*)d_in[14];
  const float* updW2 = (const float*)d_in[15];
  const float* updb2 = (const float*)d_in[16];
  const float* rW1 = (const float*)d_in[17];
  const float* rb1 = (const float*)d_in[18];
  const float* rW2 = (const float*)d_in[19];
  const float* rb2 = (const float*)d_in[20];

  float* ws = (float*)d_ws;
  float* s = ws;      ws += (size_t)NA * FDIM;
  float* vA = ws;     ws += (size_t)NA * 3 * FDIM;
  float* vB = ws;     ws += (size_t)NA * 3 * FDIM;
  float* rbfc = ws;   ws += (size_t)NE * NRBF;
  float* fcut = ws;   ws += (size_t)NE;
  float* unitv = ws;  ws += (size_t)NE * 3;
  int* counts = (int*)ws;
  int* cursor = counts + NA;
  int* offs = cursor + NA;
  int* csr_eid = offs + NA + 1;
  int* csr_j = csr_eid + NE;
  unsigned short* pk = (unsigned short*)(((uintptr_t)(csr_j + NE) + 15) & ~(uintptr_t)15);
  unsigned short* pMsgW1 = pk;
  unsigned short* pMsgW2 = pMsgW1 + 3 * 128 * 128;
  unsigned short* pUpdU  = pMsgW2 + 3 * 128 * 384;
  unsigned short* pUpdV  = pUpdU + 3 * 128 * 128;
  unsigned short* pUpdW1 = pUpdV + 3 * 128 * 128;
  unsigned short* pUpdW2 = pUpdW1 + 3 * 256 * 128;
  unsigned short* pRW1   = pUpdW2 + 3 * 128 * 384;
  unsigned short* phi_bf = pRW1 + 128 * 64;          // NA*384 bf16
  unsigned short* vbfA   = phi_bf + (size_t)NA * F3;
  unsigned short* vbfB   = vbfA + (size_t)NA * F3;

  hipMemsetAsync(counts, 0, 2 * NA * sizeof(int), stream);
  hipMemsetAsync(d_out, 0, NMOLS * sizeof(float), stream);
  hipMemsetAsync(vbfA, 0, (size_t)NA * F3 * sizeof(unsigned short), stream);

  pack_kernel<<<(3 * 128 * 128 + 255) / 256, 256, 0, stream>>>(msgW1, pMsgW1, 128, 128, 3);
  pack_kernel<<<(3 * 128 * 384 + 255) / 256, 256, 0, stream>>>(msgW2, pMsgW2, 128, 384, 3);
  pack_kernel<<<(3 * 128 * 128 + 255) / 256, 256, 0, stream>>>(updU, pUpdU, 128, 128, 3);
  pack_kernel<<<(3 * 128 * 128 + 255) / 256, 256, 0, stream>>>(updV, pUpdV, 128, 128, 3);
  pack_kernel<<<(3 * 256 * 128 + 255) / 256, 256, 0, stream>>>(updW1, pUpdW1, 256, 128, 3);
  pack_kernel<<<(3 * 128 * 384 + 255) / 256, 256, 0, stream>>>(updW2, pUpdW2, 128, 384, 3);
  pack_kernel<<<(128 * 64 + 255) / 256, 256, 0, stream>>>(rW1, pRW1, 128, 64, 1);

  geom_kernel<<<NE / 256, 256, 0, stream>>>(xyz, nbrs, unitv, rbfc, fcut);
  count_kernel<<<NE / 256, 256, 0, stream>>>(nbrs, fcut, counts);
  scan_kernel<<<1, 1024, 0, stream>>>(counts, offs);
  fill_kernel<<<NE / 256, 256, 0, stream>>>(nbrs, fcut, offs, cursor, csr_eid, csr_j);
  init_kernel<<<(NA * 3 * FDIM + 255) / 256, 256, 0, stream>>>(emb, z, s, vA);

  float* vin = vA;
  float* vout = vB;
  unsigned short* vbfin = vbfA;
  unsigned short* vbfout = vbfB;
  for (int l = 0; l < NLAYERS; l++) {
    msg_mfma_kernel<<<NA / 16, 256, 0, stream>>>(
        s, pMsgW1 + (size_t)l * 128 * 128, msgb1 + (size_t)l * FDIM,
        pMsgW2 + (size_t)l * 128 * 384, msgb2 + (size_t)l * F3, phi_bf);
    edge_kernel<<<NA, 128, 0, stream>>>(phi_bf, vin, vbfin, vout, vbfout, s,
                                        distW + (size_t)l * NRBF * F3,
                                        distb + (size_t)l * F3,
                                        offs, csr_eid, csr_j, rbfc, fcut, unitv);
    upd_mfma_kernel<<<NA / 16, 256, 0, stream>>>(
        s, vout, vbfout, pUpdU + (size_t)l * 128 * 128, pUpdV + (size_t)l * 128 * 128,
        pUpdW1 + (size_t)l * 256 * 128, updb1 + (size_t)l * FDIM,
        pUpdW2 + (size_t)l * 128 * 384, updb2 + (size_t)l * F3);
    float* tmp = vin; vin = vout; vout = tmp;
    unsigned short* tb = vbfin; vbfin = vbfout; vbfout = tb;
  }
  readout_mfma_kernel<<<NA / 16, 256, 0, stream>>>(s, pRW1, rb1, rW2, rb2, mol, (float*)d_out);
}

// Round 5
// 412.561 us; speedup vs baseline: 1.1163x; 1.1163x over previous
//
#include <hip/hip_runtime.h>
#include <hip/hip_bf16.h>
#include <math.h>

#define NA 10000
#define NE 256000
#define FDIM 128
#define F3 384
#define NRBF 20
#define NLAYERS 3
#define NMOLS 100
#define CAP 96
#define CUTOFF_F 5.0f
#define EPS_F 1e-8f
#define PI_F 3.14159265358979323846f

typedef __attribute__((ext_vector_type(8))) short bf16x8;
typedef __attribute__((ext_vector_type(4))) float f32x4;

__device__ __forceinline__ float silu_f(float x) { return x / (1.0f + expf(-x)); }

__device__ __forceinline__ unsigned short f2bf(float x) {
  unsigned u = __float_as_uint(x);
  return (unsigned short)((u + 0x7FFFu + ((u >> 16) & 1u)) >> 16);
}
__device__ __forceinline__ float bf2f(unsigned short u) {
  return __uint_as_float(((unsigned)u) << 16);
}

// ---------------- fused geometry + bucket build (replaces geom/count/scan/fill) ----------------
__global__ __launch_bounds__(256) void geom_build_kernel(
    const float* __restrict__ xyz, const int* __restrict__ nbrs,
    float* __restrict__ unitv, float* __restrict__ rbfc, float* __restrict__ fcut,
    int* __restrict__ deg, int* __restrict__ slot_e, int* __restrict__ slot_j) {
  int e = blockIdx.x * 256 + threadIdx.x;
  if (e >= NE) return;
  int i = nbrs[2 * e + 0], j = nbrs[2 * e + 1];
  float rx = xyz[3 * j + 0] - xyz[3 * i + 0];
  float ry = xyz[3 * j + 1] - xyz[3 * i + 1];
  float rz = xyz[3 * j + 2] - xyz[3 * i + 2];
  float d = sqrtf(rx * rx + ry * ry + rz * rz + EPS_F);
  if (d >= CUTOFF_F) return;  // fcut==0 -> edge contributes nothing
  float invd = 1.0f / d;
  float fc = 0.5f * (cosf(PI_F * d / CUTOFF_F) + 1.0f);
  unitv[3 * e + 0] = rx * invd;
  unitv[3 * e + 1] = ry * invd;
  unitv[3 * e + 2] = rz * invd;
  fcut[e] = fc;
  float base = PI_F * d / CUTOFF_F;
  float sc = invd;  // fcut folded into w later via l_fc; rbfc = sin(n pi d/c)/d
#pragma unroll
  for (int k = 0; k < NRBF; k++) rbfc[(size_t)e * NRBF + k] = sinf((float)(k + 1) * base) * sc;
  int pos = atomicAdd(&deg[i], 1);
  if (pos < CAP) {
    slot_e[i * CAP + pos] = e;
    slot_j[i * CAP + pos] = j;
  }
}

// ---------------- init: s = emb[z], vbfA = 0 ----------------
__global__ __launch_bounds__(256) void init_kernel(
    const float* __restrict__ emb, const int* __restrict__ z,
    float* __restrict__ s, unsigned short* __restrict__ vbfA) {
  int t = blockIdx.x * 256 + threadIdx.x;
  if (t < NA * F3) vbfA[t] = 0;
  if (t < NA * FDIM) {
    int n = t >> 7, f = t & 127;
    s[t] = emb[z[n] * FDIM + f];
  }
}

// ---------------- single fused weight pack: 7 regions -> B-fragment bf16 layout ----------------
__device__ __forceinline__ void pack_one(const float* __restrict__ src,
                                         unsigned short* __restrict__ dst,
                                         int loc, int per, int N) {
  int lay = loc / per;
  int kn = loc - lay * per;
  int k = kn / N, n = kn - k * N;
  int kb = k >> 5, q = (k >> 3) & 3, j = k & 7, nt = n >> 4, c = n & 15;
  int NT = N >> 4;
  dst[(size_t)lay * per + (((kb * NT + nt) * 64 + (q * 16 + c)) * 8 + j)] = f2bf(src[loc]);
}

__global__ __launch_bounds__(256) void pack_all_kernel(
    const float* __restrict__ msgW1, const float* __restrict__ msgW2,
    const float* __restrict__ updU, const float* __restrict__ updV,
    const float* __restrict__ updW1, const float* __restrict__ updW2,
    const float* __restrict__ rW1, unsigned short* __restrict__ dst) {
  int t = blockIdx.x * 256 + threadIdx.x;
  if (t < 49152) pack_one(msgW1, dst, t, 16384, 128);
  else if (t < 196608) pack_one(msgW2, dst + 49152, t - 49152, 49152, 384);
  else if (t < 245760) pack_one(updU, dst + 196608, t - 196608, 16384, 128);
  else if (t < 294912) pack_one(updV, dst + 245760, t - 245760, 16384, 128);
  else if (t < 393216) pack_one(updW1, dst + 294912, t - 294912, 32768, 128);
  else if (t < 540672) pack_one(updW2, dst + 393216, t - 393216, 49152, 384);
  else if (t < 548864) pack_one(rW1, dst + 540672, t - 540672, 8192, 64);
}

// ---------------- message MLP via MFMA: phi(bf16) = silu(s@W1+b1)@W2+b2 ----------------
__global__ __launch_bounds__(256) void msg_mfma_kernel(
    const float* __restrict__ s, const unsigned short* __restrict__ pW1,
    const float* __restrict__ b1, const unsigned short* __restrict__ pW2,
    const float* __restrict__ b2, unsigned short* __restrict__ phi_bf) {
  __shared__ bf16x8 sA[4 * 64];
  __shared__ bf16x8 hA[4 * 64];
  int a0 = blockIdx.x * 16;
  int t = threadIdx.x;
  int lane = t & 63, w = t >> 6;
  {
    int kb = t >> 6, l = t & 63;
    int m = l & 15, q = l >> 4;
    const float* sp = s + (size_t)(a0 + m) * FDIM + kb * 32 + q * 8;
    bf16x8 c;
#pragma unroll
    for (int j = 0; j < 8; j++) c[j] = (short)f2bf(sp[j]);
    sA[kb * 64 + l] = c;
  }
  __syncthreads();
  f32x4 accH[2];
#pragma unroll
  for (int t2 = 0; t2 < 2; t2++)
#pragma unroll
    for (int r = 0; r < 4; r++) accH[t2][r] = 0.0f;
  const bf16x8* W1f = (const bf16x8*)pW1;
#pragma unroll
  for (int kb = 0; kb < 4; kb++) {
    bf16x8 a = sA[kb * 64 + lane];
#pragma unroll
    for (int t2 = 0; t2 < 2; t2++) {
      bf16x8 b = W1f[(kb * 8 + 2 * w + t2) * 64 + lane];
      accH[t2] = __builtin_amdgcn_mfma_f32_16x16x32_bf16(a, b, accH[t2], 0, 0, 0);
    }
  }
  short* hs = (short*)hA;
#pragma unroll
  for (int t2 = 0; t2 < 2; t2++) {
    int n = w * 32 + t2 * 16 + (lane & 15);
    int kb = n >> 5, q = (n >> 3) & 3, j = n & 7;
    float bias = b1[n];
#pragma unroll
    for (int r = 0; r < 4; r++) {
      int m = (lane >> 4) * 4 + r;
      hs[(kb * 64 + q * 16 + m) * 8 + j] = (short)f2bf(silu_f(accH[t2][r] + bias));
    }
  }
  __syncthreads();
  f32x4 accP[6];
#pragma unroll
  for (int t6 = 0; t6 < 6; t6++)
#pragma unroll
    for (int r = 0; r < 4; r++) accP[t6][r] = 0.0f;
  const bf16x8* W2f = (const bf16x8*)pW2;
#pragma unroll
  for (int kb = 0; kb < 4; kb++) {
    bf16x8 a = hA[kb * 64 + lane];
#pragma unroll
    for (int t6 = 0; t6 < 6; t6++) {
      bf16x8 b = W2f[(kb * 24 + 6 * w + t6) * 64 + lane];
      accP[t6] = __builtin_amdgcn_mfma_f32_16x16x32_bf16(a, b, accP[t6], 0, 0, 0);
    }
  }
#pragma unroll
  for (int t6 = 0; t6 < 6; t6++) {
    int n = (6 * w + t6) * 16 + (lane & 15);
    float bias = b2[n];
#pragma unroll
    for (int r = 0; r < 4; r++) {
      int m = (lane >> 4) * 4 + r;
      phi_bf[(size_t)(a0 + m) * F3 + n] = f2bf(accP[t6][r] + bias);
    }
  }
}

// ---------------- edge aggregation: LDS metadata staging, bf16 gathers, bucket list ----------------
__global__ __launch_bounds__(128) void edge_kernel(
    const unsigned short* __restrict__ phi_bf, const unsigned short* __restrict__ vbf_in,
    unsigned short* __restrict__ vbf_out, float* __restrict__ s,
    const float* __restrict__ dW, const float* __restrict__ db,
    const int* __restrict__ deg, const int* __restrict__ slot_e,
    const int* __restrict__ slot_j, const float* __restrict__ rbfc,
    const float* __restrict__ fcut, const float* __restrict__ unitv) {
  __shared__ float l_rbf[CAP][NRBF];
  __shared__ float l_u[CAP][3];
  __shared__ float l_fc[CAP];
  __shared__ int l_j[CAP];
  int i = blockIdx.x;
  int f = threadIdx.x;
  int cnt = deg[i];
  if (cnt > CAP) cnt = CAP;
  int base = i * CAP;
  for (int q = f; q < cnt; q += 128) {
    int e = slot_e[base + q];
    l_j[q] = slot_j[base + q];
    l_fc[q] = fcut[e];
    l_u[q][0] = unitv[3 * e + 0];
    l_u[q][1] = unitv[3 * e + 1];
    l_u[q][2] = unitv[3 * e + 2];
  }
  for (int q = f; q < cnt * NRBF; q += 128) {
    int p = q / NRBF, k = q - p * NRBF;
    l_rbf[p][k] = rbfc[(size_t)slot_e[base + p] * NRBF + k];
  }
  float wd0[NRBF], wd1[NRBF], wd2[NRBF];
#pragma unroll
  for (int k = 0; k < NRBF; k++) {
    wd0[k] = dW[k * F3 + f];
    wd1[k] = dW[k * F3 + FDIM + f];
    wd2[k] = dW[k * F3 + 2 * FDIM + f];
  }
  float db0 = db[f], db1 = db[FDIM + f], db2 = db[2 * FDIM + f];
  __syncthreads();
  float acc_s = 0.f, av0 = 0.f, av1 = 0.f, av2 = 0.f;
  int p = 0;
  for (; p + 2 <= cnt; p += 2) {
    int j0 = l_j[p], j1 = l_j[p + 1];
    const unsigned short* ph0 = phi_bf + (size_t)j0 * F3;
    const unsigned short* ph1 = phi_bf + (size_t)j1 * F3;
    const unsigned short* vj0 = vbf_in + (size_t)j0 * F3;
    const unsigned short* vj1 = vbf_in + (size_t)j1 * F3;
    // issue all 12 gathers first; the 120-FMA w-chain below hides their latency
    float p00 = bf2f(ph0[f]), p01 = bf2f(ph0[FDIM + f]), p02 = bf2f(ph0[2 * FDIM + f]);
    float p10 = bf2f(ph1[f]), p11 = bf2f(ph1[FDIM + f]), p12 = bf2f(ph1[2 * FDIM + f]);
    float v00 = bf2f(vj0[f]), v01 = bf2f(vj0[FDIM + f]), v02 = bf2f(vj0[2 * FDIM + f]);
    float v10 = bf2f(vj1[f]), v11 = bf2f(vj1[FDIM + f]), v12 = bf2f(vj1[2 * FDIM + f]);
    float fc0 = l_fc[p], fc1 = l_fc[p + 1];
    float w00 = db0 * fc0, w01 = db1 * fc0, w02 = db2 * fc0;
    float w10 = db0 * fc1, w11 = db1 * fc1, w12 = db2 * fc1;
#pragma unroll
    for (int k = 0; k < NRBF; k++) {
      float r0 = l_rbf[p][k] * fc0, r1 = l_rbf[p + 1][k] * fc1;
      w00 += r0 * wd0[k]; w01 += r0 * wd1[k]; w02 += r0 * wd2[k];
      w10 += r1 * wd0[k]; w11 += r1 * wd1[k]; w12 += r1 * wd2[k];
    }
    acc_s += p00 * w00 + p10 * w10;
    float i01 = p01 * w01, i02 = p02 * w02, i11 = p11 * w11, i12 = p12 * w12;
    av0 += i01 * v00 + i02 * l_u[p][0] + i11 * v10 + i12 * l_u[p + 1][0];
    av1 += i01 * v01 + i02 * l_u[p][1] + i11 * v11 + i12 * l_u[p + 1][1];
    av2 += i01 * v02 + i02 * l_u[p][2] + i11 * v12 + i12 * l_u[p + 1][2];
  }
  if (p < cnt) {
    int j0 = l_j[p];
    const unsigned short* ph0 = phi_bf + (size_t)j0 * F3;
    const unsigned short* vj0 = vbf_in + (size_t)j0 * F3;
    float p00 = bf2f(ph0[f]), p01 = bf2f(ph0[FDIM + f]), p02 = bf2f(ph0[2 * FDIM + f]);
    float v00 = bf2f(vj0[f]), v01 = bf2f(vj0[FDIM + f]), v02 = bf2f(vj0[2 * FDIM + f]);
    float fc0 = l_fc[p];
    float w00 = db0 * fc0, w01 = db1 * fc0, w02 = db2 * fc0;
#pragma unroll
    for (int k = 0; k < NRBF; k++) {
      float r0 = l_rbf[p][k] * fc0;
      w00 += r0 * wd0[k]; w01 += r0 * wd1[k]; w02 += r0 * wd2[k];
    }
    acc_s += p00 * w00;
    float i01 = p01 * w01, i02 = p02 * w02;
    av0 += i01 * v00 + i02 * l_u[p][0];
    av1 += i01 * v01 + i02 * l_u[p][1];
    av2 += i01 * v02 + i02 * l_u[p][2];
  }
  const unsigned short* vbi = vbf_in + (size_t)i * F3;
  unsigned short* vbo = vbf_out + (size_t)i * F3;
  vbo[f] = f2bf(bf2f(vbi[f]) + av0);
  vbo[FDIM + f] = f2bf(bf2f(vbi[FDIM + f]) + av1);
  vbo[2 * FDIM + f] = f2bf(bf2f(vbi[2 * FDIM + f]) + av2);
  s[(size_t)i * FDIM + f] += acc_s;
}

// ---------------- update block via MFMA (v is bf16-only) ----------------
__global__ __launch_bounds__(256) void upd_mfma_kernel(
    float* __restrict__ s, unsigned short* __restrict__ vbf,
    const unsigned short* __restrict__ pU, const unsigned short* __restrict__ pV,
    const unsigned short* __restrict__ pW1, const float* __restrict__ b1,
    const unsigned short* __restrict__ pW2, const float* __restrict__ b2) {
  __shared__ bf16x8 vAf[3 * 4 * 64];
  __shared__ bf16x8 catA[8 * 64];
  __shared__ bf16x8 hA[4 * 64];
  int a0 = blockIdx.x * 16;
  int t = threadIdx.x;
  int lane = t & 63, w = t >> 6;
  {
    int l = t & 63, kb = (t >> 6) & 3;
    int m = l & 15, q = l >> 4;
#pragma unroll
    for (int rt = 0; rt < 3; rt++) {
      vAf[(rt * 4 + kb) * 64 + l] =
          *(const bf16x8*)(vbf + (size_t)(a0 + m) * F3 + rt * FDIM + kb * 32 + q * 8);
    }
    const float* sp = s + (size_t)(a0 + m) * FDIM + kb * 32 + q * 8;
    bf16x8 c;
#pragma unroll
    for (int j = 0; j < 8; j++) c[j] = (short)f2bf(sp[j]);
    catA[kb * 64 + l] = c;
  }
  __syncthreads();
  f32x4 accU[3][2], accV[3][2];
#pragma unroll
  for (int rt = 0; rt < 3; rt++)
#pragma unroll
    for (int t2 = 0; t2 < 2; t2++)
#pragma unroll
      for (int r = 0; r < 4; r++) { accU[rt][t2][r] = 0.0f; accV[rt][t2][r] = 0.0f; }
  const bf16x8* Uf = (const bf16x8*)pU;
  const bf16x8* Vf = (const bf16x8*)pV;
#pragma unroll
  for (int kb = 0; kb < 4; kb++) {
    bf16x8 bu[2], bv[2];
#pragma unroll
    for (int t2 = 0; t2 < 2; t2++) {
      bu[t2] = Uf[(kb * 8 + 2 * w + t2) * 64 + lane];
      bv[t2] = Vf[(kb * 8 + 2 * w + t2) * 64 + lane];
    }
#pragma unroll
    for (int rt = 0; rt < 3; rt++) {
      bf16x8 a = vAf[(rt * 4 + kb) * 64 + lane];
#pragma unroll
      for (int t2 = 0; t2 < 2; t2++) {
        accU[rt][t2] = __builtin_amdgcn_mfma_f32_16x16x32_bf16(a, bu[t2], accU[rt][t2], 0, 0, 0);
        accV[rt][t2] = __builtin_amdgcn_mfma_f32_16x16x32_bf16(a, bv[t2], accV[rt][t2], 0, 0, 0);
      }
    }
  }
  short* cs = (short*)catA;
#pragma unroll
  for (int t2 = 0; t2 < 2; t2++) {
    int g = w * 32 + t2 * 16 + (lane & 15);
    int k = 128 + g;
    int kb = k >> 5, q = (k >> 3) & 3, j = k & 7;
#pragma unroll
    for (int r = 0; r < 4; r++) {
      int m = (lane >> 4) * 4 + r;
      float x0 = accV[0][t2][r], x1 = accV[1][t2][r], x2 = accV[2][t2][r];
      cs[(kb * 64 + q * 16 + m) * 8 + j] = (short)f2bf(sqrtf(x0 * x0 + x1 * x1 + x2 * x2 + EPS_F));
    }
  }
  __syncthreads();
  f32x4 accH[2];
#pragma unroll
  for (int t2 = 0; t2 < 2; t2++)
#pragma unroll
    for (int r = 0; r < 4; r++) accH[t2][r] = 0.0f;
  const bf16x8* W1f = (const bf16x8*)pW1;
#pragma unroll
  for (int kb = 0; kb < 8; kb++) {
    bf16x8 a = catA[kb * 64 + lane];
#pragma unroll
    for (int t2 = 0; t2 < 2; t2++) {
      bf16x8 b = W1f[(kb * 8 + 2 * w + t2) * 64 + lane];
      accH[t2] = __builtin_amdgcn_mfma_f32_16x16x32_bf16(a, b, accH[t2], 0, 0, 0);
    }
  }
  short* hs = (short*)hA;
#pragma unroll
  for (int t2 = 0; t2 < 2; t2++) {
    int n = w * 32 + t2 * 16 + (lane & 15);
    int kb = n >> 5, q = (n >> 3) & 3, j = n & 7;
    float bias = b1[n];
#pragma unroll
    for (int r = 0; r < 4; r++) {
      int m = (lane >> 4) * 4 + r;
      hs[(kb * 64 + q * 16 + m) * 8 + j] = (short)f2bf(silu_f(accH[t2][r] + bias));
    }
  }
  __syncthreads();
  f32x4 accA[3][2];
#pragma unroll
  for (int c3 = 0; c3 < 3; c3++)
#pragma unroll
    for (int t2 = 0; t2 < 2; t2++)
#pragma unroll
      for (int r = 0; r < 4; r++) accA[c3][t2][r] = 0.0f;
  const bf16x8* W2f = (const bf16x8*)pW2;
#pragma unroll
  for (int kb = 0; kb < 4; kb++) {
    bf16x8 a = hA[kb * 64 + lane];
#pragma unroll
    for (int c3 = 0; c3 < 3; c3++)
#pragma unroll
      for (int t2 = 0; t2 < 2; t2++) {
        bf16x8 b = W2f[(kb * 24 + c3 * 8 + 2 * w + t2) * 64 + lane];
        accA[c3][t2] = __builtin_amdgcn_mfma_f32_16x16x32_bf16(a, b, accA[c3][t2], 0, 0, 0);
      }
  }
#pragma unroll
  for (int t2 = 0; t2 < 2; t2++) {
    int g = w * 32 + t2 * 16 + (lane & 15);
    float bb0 = b2[g], bb1 = b2[FDIM + g], bb2 = b2[2 * FDIM + g];
#pragma unroll
    for (int r = 0; r < 4; r++) {
      int m = (lane >> 4) * 4 + r;
      int n = a0 + m;
      float a0v = accA[0][t2][r] + bb0;
      float a1v = accA[1][t2][r] + bb1;
      float a2v = accA[2][t2][r] + bb2;
      float dot = accU[0][t2][r] * accV[0][t2][r] + accU[1][t2][r] * accV[1][t2][r] +
                  accU[2][t2][r] * accV[2][t2][r];
      s[(size_t)n * FDIM + g] += a1v * dot + a2v;
#pragma unroll
      for (int c = 0; c < 3; c++) {
        size_t ix = (size_t)n * F3 + c * FDIM + g;
        vbf[ix] = f2bf(bf2f(vbf[ix]) + a0v * accU[c][t2][r]);
      }
    }
  }
}

// ---------------- readout via MFMA ----------------
__global__ __launch_bounds__(256) void readout_mfma_kernel(
    const float* __restrict__ s, const unsigned short* __restrict__ pW1,
    const float* __restrict__ b1, const float* __restrict__ W2, const float* __restrict__ b2,
    const int* __restrict__ mol_idx, float* __restrict__ out) {
  __shared__ bf16x8 sA[4 * 64];
  __shared__ float red[4][16];
  int a0 = blockIdx.x * 16;
  int t = threadIdx.x;
  int lane = t & 63, w = t >> 6;
  {
    int kb = t >> 6, l = t & 63;
    int m = l & 15, q = l >> 4;
    const float* sp = s + (size_t)(a0 + m) * FDIM + kb * 32 + q * 8;
    bf16x8 c;
#pragma unroll
    for (int j = 0; j < 8; j++) c[j] = (short)f2bf(sp[j]);
    sA[kb * 64 + l] = c;
  }
  __syncthreads();
  f32x4 acc;
#pragma unroll
  for (int r = 0; r < 4; r++) acc[r] = 0.0f;
  const bf16x8* W1f = (const bf16x8*)pW1;
#pragma unroll
  for (int kb = 0; kb < 4; kb++) {
    bf16x8 a = sA[kb * 64 + lane];
    bf16x8 b = W1f[(kb * 4 + w) * 64 + lane];
    acc = __builtin_amdgcn_mfma_f32_16x16x32_bf16(a, b, acc, 0, 0, 0);
  }
  int col = w * 16 + (lane & 15);
  float bias = b1[col], w2v = W2[col];
  float val[4];
#pragma unroll
  for (int r = 0; r < 4; r++) val[r] = silu_f(acc[r] + bias) * w2v;
#pragma unroll
  for (int off = 1; off < 16; off <<= 1)
#pragma unroll
    for (int r = 0; r < 4; r++) val[r] += __shfl_xor(val[r], off, 64);
  if ((lane & 15) == 0) {
#pragma unroll
    for (int r = 0; r < 4; r++) red[w][(lane >> 4) * 4 + r] = val[r];
  }
  __syncthreads();
  if (t < 16) {
    float sum = red[0][t] + red[1][t] + red[2][t] + red[3][t] + b2[0];
    atomicAdd(&out[mol_idx[a0 + t]], sum);
  }
}

extern "C" void kernel_launch(void* const* d_in, const int* in_sizes, int n_in,
                              void* d_out, int out_size, void* d_ws, size_t ws_size,
                              hipStream_t stream) {
  const float* xyz = (const float*)d_in[0];
  const int* z = (const int*)d_in[1];
  const int* nbrs = (const int*)d_in[2];
  const int* mol = (const int*)d_in[3];
  const float* emb = (const float*)d_in[4];
  const float* msgW1 = (const float*)d_in[5];
  const float* msgb1 = (const float*)d_in[6];
  const float* msgW2 = (const float*)d_in[7];
  const float* msgb2 = (const float*)d_in[8];
  const float* distW = (const float*)d_in[9];
  const float* distb = (const float*)d_in[10];
  const float* updU = (const float*)d_in[11];
  const float* updV = (const float*)d_in[12];
  const float* updW1 = (const float*)d_in[13];
  const float* updb1 = (const float*)d_in[14];
  const float* updW2 = (const float*)d_in[15];
  const float* updb2 = (const float*)d_in[16];
  const float* rW1 = (const float*)d_in[17];
  const float* rb1 = (const float*)d_in[18];
  const float* rW2 = (const float*)d_in[19];
  const float* rb2 = (const float*)d_in[20];

  float* ws = (float*)d_ws;
  float* s = ws;      ws += (size_t)NA * FDIM;
  float* rbfc = ws;   ws += (size_t)NE * NRBF;
  float* fcut = ws;   ws += (size_t)NE;
  float* unitv = ws;  ws += (size_t)NE * 3;
  int* deg = (int*)ws;
  int* slot_e = deg + NA;
  int* slot_j = slot_e + NA * CAP;
  unsigned short* pk = (unsigned short*)(((uintptr_t)(slot_j + NA * CAP) + 15) & ~(uintptr_t)15);
  unsigned short* pMsgW1 = pk;                       // 49152
  unsigned short* pMsgW2 = pMsgW1 + 49152;           // 147456
  unsigned short* pUpdU  = pMsgW2 + 147456;          // 49152
  unsigned short* pUpdV  = pUpdU + 49152;            // 49152
  unsigned short* pUpdW1 = pUpdV + 49152;            // 98304
  unsigned short* pUpdW2 = pUpdW1 + 98304;           // 147456
  unsigned short* pRW1   = pUpdW2 + 147456;          // 8192
  unsigned short* phi_bf = (unsigned short*)(((uintptr_t)(pRW1 + 8192) + 15) & ~(uintptr_t)15);
  unsigned short* vbfA   = phi_bf + (size_t)NA * F3;
  unsigned short* vbfB   = vbfA + (size_t)NA * F3;

  hipMemsetAsync(deg, 0, NA * sizeof(int), stream);
  hipMemsetAsync(d_out, 0, NMOLS * sizeof(float), stream);

  pack_all_kernel<<<(548864 + 255) / 256, 256, 0, stream>>>(
      msgW1, msgW2, updU, updV, updW1, updW2, rW1, pMsgW1);
  geom_build_kernel<<<NE / 256, 256, 0, stream>>>(xyz, nbrs, unitv, rbfc, fcut,
                                                  deg, slot_e, slot_j);
  init_kernel<<<(NA * F3 + 255) / 256, 256, 0, stream>>>(emb, z, s, vbfA);

  unsigned short* vbfin = vbfA;
  unsigned short* vbfout = vbfB;
  for (int l = 0; l < NLAYERS; l++) {
    msg_mfma_kernel<<<NA / 16, 256, 0, stream>>>(
        s, pMsgW1 + (size_t)l * 16384, msgb1 + (size_t)l * FDIM,
        pMsgW2 + (size_t)l * 49152, msgb2 + (size_t)l * F3, phi_bf);
    edge_kernel<<<NA, 128, 0, stream>>>(phi_bf, vbfin, vbfout, s,
                                        distW + (size_t)l * NRBF * F3,
                                        distb + (size_t)l * F3,
                                        deg, slot_e, slot_j, rbfc, fcut, unitv);
    upd_mfma_kernel<<<NA / 16, 256, 0, stream>>>(
        s, vbfout, pUpdU + (size_t)l * 16384, pUpdV + (size_t)l * 16384,
        pUpdW1 + (size_t)l * 32768, updb1 + (size_t)l * FDIM,
        pUpdW2 + (size_t)l * 49152, updb2 + (size_t)l * F3);
    unsigned short* tb = vbfin; vbfin = vbfout; vbfout = tb;
  }
  readout_mfma_kernel<<<NA / 16, 256, 0, stream>>>(s, pRW1, rb1, rW2, rb2, mol, (float*)d_out);
}

// Round 6
// 387.476 us; speedup vs baseline: 1.1886x; 1.0647x over previous
//
#include <hip/hip_runtime.h>
#include <hip/hip_bf16.h>
#include <math.h>

#define NA 10000
#define NE 256000
#define FDIM 128
#define F3 384
#define NRBF 20
#define NLAYERS 3
#define NMOLS 100
#define CAP 96
#define WROW 388  // padded w_lds row (bf16): 388*2/4 % 32 == 2 -> conflict-free transpose
#define CUTOFF_F 5.0f
#define EPS_F 1e-8f
#define PI_F 3.14159265358979323846f

typedef __attribute__((ext_vector_type(8))) short bf16x8;
typedef __attribute__((ext_vector_type(4))) float f32x4;

__device__ __forceinline__ float silu_f(float x) { return x / (1.0f + expf(-x)); }

__device__ __forceinline__ unsigned short f2bf(float x) {
  unsigned u = __float_as_uint(x);
  return (unsigned short)((u + 0x7FFFu + ((u >> 16) & 1u)) >> 16);
}
__device__ __forceinline__ float bf2f(unsigned short u) {
  return __uint_as_float(((unsigned)u) << 16);
}

// ---------------- fused geometry + bucket build ----------------
__global__ __launch_bounds__(256) void geom_build_kernel(
    const float* __restrict__ xyz, const int* __restrict__ nbrs,
    float* __restrict__ unitv, float* __restrict__ rbfc, float* __restrict__ fcut,
    int* __restrict__ deg, int* __restrict__ slot_e, int* __restrict__ slot_j) {
  int e = blockIdx.x * 256 + threadIdx.x;
  if (e >= NE) return;
  int i = nbrs[2 * e + 0], j = nbrs[2 * e + 1];
  float rx = xyz[3 * j + 0] - xyz[3 * i + 0];
  float ry = xyz[3 * j + 1] - xyz[3 * i + 1];
  float rz = xyz[3 * j + 2] - xyz[3 * i + 2];
  float d = sqrtf(rx * rx + ry * ry + rz * rz + EPS_F);
  if (d >= CUTOFF_F) return;
  float invd = 1.0f / d;
  float fc = 0.5f * (cosf(PI_F * d / CUTOFF_F) + 1.0f);
  unitv[3 * e + 0] = rx * invd;
  unitv[3 * e + 1] = ry * invd;
  unitv[3 * e + 2] = rz * invd;
  fcut[e] = fc;
  float base = PI_F * d / CUTOFF_F;
#pragma unroll
  for (int k = 0; k < NRBF; k++) rbfc[(size_t)e * NRBF + k] = sinf((float)(k + 1) * base) * invd;
  int pos = atomicAdd(&deg[i], 1);
  if (pos < CAP) {
    slot_e[i * CAP + pos] = e;
    slot_j[i * CAP + pos] = j;
  }
}

// ---------------- init: s = emb[z], vbfA = 0 ----------------
__global__ __launch_bounds__(256) void init_kernel(
    const float* __restrict__ emb, const int* __restrict__ z,
    float* __restrict__ s, unsigned short* __restrict__ vbfA) {
  int t = blockIdx.x * 256 + threadIdx.x;
  if (t < NA * F3) vbfA[t] = 0;
  if (t < NA * FDIM) {
    int n = t >> 7, f = t & 127;
    s[t] = emb[z[n] * FDIM + f];
  }
}

// ---------------- single fused weight pack -> B-fragment bf16 layout ----------------
__device__ __forceinline__ void pack_one(const float* __restrict__ src,
                                         unsigned short* __restrict__ dst,
                                         int loc, int per, int N) {
  int lay = loc / per;
  int kn = loc - lay * per;
  int k = kn / N, n = kn - k * N;
  int kb = k >> 5, q = (k >> 3) & 3, j = k & 7, nt = n >> 4, c = n & 15;
  int NT = N >> 4;
  dst[(size_t)lay * per + (((kb * NT + nt) * 64 + (q * 16 + c)) * 8 + j)] = f2bf(src[loc]);
}

// dist_W padded pack: K=32 (rows 0..19 = dW, row 20 = db, rest 0), N=384
__device__ __forceinline__ void pack_dw(const float* __restrict__ dW,
                                        const float* __restrict__ db,
                                        unsigned short* __restrict__ dst, int loc) {
  int lay = loc / 12288;
  int kn = loc - lay * 12288;
  int k = kn / 384, n = kn - k * 384;
  float val = 0.0f;
  if (k < NRBF) val = dW[lay * NRBF * 384 + k * 384 + n];
  else if (k == NRBF) val = db[lay * 384 + n];
  int q = (k >> 3) & 3, j = k & 7, nt = n >> 4, c = n & 15;
  dst[(size_t)lay * 12288 + ((nt * 64 + (q * 16 + c)) * 8 + j)] = f2bf(val);
}

__global__ __launch_bounds__(256) void pack_all_kernel(
    const float* __restrict__ msgW1, const float* __restrict__ msgW2,
    const float* __restrict__ updU, const float* __restrict__ updV,
    const float* __restrict__ updW1, const float* __restrict__ updW2,
    const float* __restrict__ rW1, const float* __restrict__ distW,
    const float* __restrict__ distb, unsigned short* __restrict__ dst) {
  int t = blockIdx.x * 256 + threadIdx.x;
  if (t < 49152) pack_one(msgW1, dst, t, 16384, 128);
  else if (t < 196608) pack_one(msgW2, dst + 49152, t - 49152, 49152, 384);
  else if (t < 245760) pack_one(updU, dst + 196608, t - 196608, 16384, 128);
  else if (t < 294912) pack_one(updV, dst + 245760, t - 245760, 16384, 128);
  else if (t < 393216) pack_one(updW1, dst + 294912, t - 294912, 32768, 128);
  else if (t < 540672) pack_one(updW2, dst + 393216, t - 393216, 49152, 384);
  else if (t < 548864) pack_one(rW1, dst + 540672, t - 540672, 8192, 64);
  else if (t < 585728) pack_dw(distW, distb, dst + 548864, t - 548864);
}

// ---------------- message MLP via MFMA: phi(bf16) = silu(s@W1+b1)@W2+b2 ----------------
__global__ __launch_bounds__(256) void msg_mfma_kernel(
    const float* __restrict__ s, const unsigned short* __restrict__ pW1,
    const float* __restrict__ b1, const unsigned short* __restrict__ pW2,
    const float* __restrict__ b2, unsigned short* __restrict__ phi_bf) {
  __shared__ bf16x8 sA[4 * 64];
  __shared__ bf16x8 hA[4 * 64];
  int a0 = blockIdx.x * 16;
  int t = threadIdx.x;
  int lane = t & 63, w = t >> 6;
  {
    int kb = t >> 6, l = t & 63;
    int m = l & 15, q = l >> 4;
    const float* sp = s + (size_t)(a0 + m) * FDIM + kb * 32 + q * 8;
    bf16x8 c;
#pragma unroll
    for (int j = 0; j < 8; j++) c[j] = (short)f2bf(sp[j]);
    sA[kb * 64 + l] = c;
  }
  __syncthreads();
  f32x4 accH[2];
#pragma unroll
  for (int t2 = 0; t2 < 2; t2++)
#pragma unroll
    for (int r = 0; r < 4; r++) accH[t2][r] = 0.0f;
  const bf16x8* W1f = (const bf16x8*)pW1;
#pragma unroll
  for (int kb = 0; kb < 4; kb++) {
    bf16x8 a = sA[kb * 64 + lane];
#pragma unroll
    for (int t2 = 0; t2 < 2; t2++) {
      bf16x8 b = W1f[(kb * 8 + 2 * w + t2) * 64 + lane];
      accH[t2] = __builtin_amdgcn_mfma_f32_16x16x32_bf16(a, b, accH[t2], 0, 0, 0);
    }
  }
  short* hs = (short*)hA;
#pragma unroll
  for (int t2 = 0; t2 < 2; t2++) {
    int n = w * 32 + t2 * 16 + (lane & 15);
    int kb = n >> 5, q = (n >> 3) & 3, j = n & 7;
    float bias = b1[n];
#pragma unroll
    for (int r = 0; r < 4; r++) {
      int m = (lane >> 4) * 4 + r;
      hs[(kb * 64 + q * 16 + m) * 8 + j] = (short)f2bf(silu_f(accH[t2][r] + bias));
    }
  }
  __syncthreads();
  f32x4 accP[6];
#pragma unroll
  for (int t6 = 0; t6 < 6; t6++)
#pragma unroll
    for (int r = 0; r < 4; r++) accP[t6][r] = 0.0f;
  const bf16x8* W2f = (const bf16x8*)pW2;
#pragma unroll
  for (int kb = 0; kb < 4; kb++) {
    bf16x8 a = hA[kb * 64 + lane];
#pragma unroll
    for (int t6 = 0; t6 < 6; t6++) {
      bf16x8 b = W2f[(kb * 24 + 6 * w + t6) * 64 + lane];
      accP[t6] = __builtin_amdgcn_mfma_f32_16x16x32_bf16(a, b, accP[t6], 0, 0, 0);
    }
  }
#pragma unroll
  for (int t6 = 0; t6 < 6; t6++) {
    int n = (6 * w + t6) * 16 + (lane & 15);
    float bias = b2[n];
#pragma unroll
    for (int r = 0; r < 4; r++) {
      int m = (lane >> 4) * 4 + r;
      phi_bf[(size_t)(a0 + m) * F3 + n] = f2bf(accP[t6][r] + bias);
    }
  }
}

// ---------------- edge aggregation: per-chunk MFMA w-precompute + streamed gathers ----------------
// w[e][n] = fc*(rbf[e]@dW + db)[n] via one 16x16x32 MFMA per N-tile:
//   A[e][k] = rbf[e][k]*fc (k<20), fc (k==20), 0 (else); B = padded dW (row 20 = db).
__global__ __launch_bounds__(128) void edge_kernel(
    const unsigned short* __restrict__ phi_bf, const unsigned short* __restrict__ vbf_in,
    unsigned short* __restrict__ vbf_out, float* __restrict__ s,
    const unsigned short* __restrict__ pDW,
    const int* __restrict__ deg, const int* __restrict__ slot_e,
    const int* __restrict__ slot_j, const float* __restrict__ rbfc,
    const float* __restrict__ fcut, const float* __restrict__ unitv) {
  __shared__ bf16x8 aLDS[64];
  __shared__ unsigned short w_lds[16][WROW];
  __shared__ float l_u[16][3];
  __shared__ int l_j[16];
  int i = blockIdx.x;
  int t = threadIdx.x;
  int f = t;
  int lane = t & 63, w = t >> 6;
  int cnt = deg[i];
  if (cnt > CAP) cnt = CAP;
  int base = i * CAP;
  float acc_s = 0.f, av0 = 0.f, av1 = 0.f, av2 = 0.f;
  const bf16x8* Bf = (const bf16x8*)pDW;
  for (int c0 = 0; c0 < cnt; c0 += 16) {
    int ccnt = cnt - c0;
    if (ccnt > 16) ccnt = 16;
    __syncthreads();  // protect LDS reuse across chunks
    if (t < 64) {
      int m = t & 15, q = t >> 4;
      bf16x8 a;
#pragma unroll
      for (int j = 0; j < 8; j++) a[j] = 0;
      int p = c0 + m;
      if (p < cnt) {
        int e = slot_e[base + p];
        float fc = fcut[e];
        const float* rb = rbfc + (size_t)e * NRBF;
#pragma unroll
        for (int j = 0; j < 8; j++) {
          int k = q * 8 + j;
          float val = (k < NRBF) ? rb[k] * fc : (k == NRBF ? fc : 0.0f);
          a[j] = (short)f2bf(val);
        }
      }
      aLDS[t] = a;
    } else if (t < 80) {
      int idx = t - 64;
      int p = c0 + idx;
      if (p < cnt) {
        int e = slot_e[base + p];
        l_j[idx] = slot_j[base + p];
        l_u[idx][0] = unitv[3 * e + 0];
        l_u[idx][1] = unitv[3 * e + 1];
        l_u[idx][2] = unitv[3 * e + 2];
      }
    }
    __syncthreads();
    {
      bf16x8 a = aLDS[lane];
      int n0 = lane & 15, m0 = (lane >> 4) * 4;
#pragma unroll
      for (int tt = 0; tt < 12; tt++) {
        int nt = 12 * w + tt;
        f32x4 acc;
#pragma unroll
        for (int r = 0; r < 4; r++) acc[r] = 0.0f;
        acc = __builtin_amdgcn_mfma_f32_16x16x32_bf16(a, Bf[nt * 64 + lane], acc, 0, 0, 0);
        int n = nt * 16 + n0;
#pragma unroll
        for (int r = 0; r < 4; r++) w_lds[m0 + r][n] = f2bf(acc[r]);
      }
    }
    __syncthreads();
    int pp = 0;
    for (; pp + 2 <= ccnt; pp += 2) {
      int j0 = l_j[pp], j1 = l_j[pp + 1];
      const unsigned short* ph0 = phi_bf + (size_t)j0 * F3;
      const unsigned short* ph1 = phi_bf + (size_t)j1 * F3;
      const unsigned short* vj0 = vbf_in + (size_t)j0 * F3;
      const unsigned short* vj1 = vbf_in + (size_t)j1 * F3;
      float p00 = bf2f(ph0[f]), p01 = bf2f(ph0[FDIM + f]), p02 = bf2f(ph0[2 * FDIM + f]);
      float p10 = bf2f(ph1[f]), p11 = bf2f(ph1[FDIM + f]), p12 = bf2f(ph1[2 * FDIM + f]);
      float v00 = bf2f(vj0[f]), v01 = bf2f(vj0[FDIM + f]), v02 = bf2f(vj0[2 * FDIM + f]);
      float v10 = bf2f(vj1[f]), v11 = bf2f(vj1[FDIM + f]), v12 = bf2f(vj1[2 * FDIM + f]);
      float w00 = bf2f(w_lds[pp][f]), w01 = bf2f(w_lds[pp][FDIM + f]),
            w02 = bf2f(w_lds[pp][2 * FDIM + f]);
      float w10 = bf2f(w_lds[pp + 1][f]), w11 = bf2f(w_lds[pp + 1][FDIM + f]),
            w12 = bf2f(w_lds[pp + 1][2 * FDIM + f]);
      acc_s += p00 * w00 + p10 * w10;
      float i01 = p01 * w01, i02 = p02 * w02, i11 = p11 * w11, i12 = p12 * w12;
      av0 += i01 * v00 + i02 * l_u[pp][0] + i11 * v10 + i12 * l_u[pp + 1][0];
      av1 += i01 * v01 + i02 * l_u[pp][1] + i11 * v11 + i12 * l_u[pp + 1][1];
      av2 += i01 * v02 + i02 * l_u[pp][2] + i11 * v12 + i12 * l_u[pp + 1][2];
    }
    if (pp < ccnt) {
      int j0 = l_j[pp];
      const unsigned short* ph0 = phi_bf + (size_t)j0 * F3;
      const unsigned short* vj0 = vbf_in + (size_t)j0 * F3;
      float p00 = bf2f(ph0[f]), p01 = bf2f(ph0[FDIM + f]), p02 = bf2f(ph0[2 * FDIM + f]);
      float v00 = bf2f(vj0[f]), v01 = bf2f(vj0[FDIM + f]), v02 = bf2f(vj0[2 * FDIM + f]);
      float w00 = bf2f(w_lds[pp][f]), w01 = bf2f(w_lds[pp][FDIM + f]),
            w02 = bf2f(w_lds[pp][2 * FDIM + f]);
      acc_s += p00 * w00;
      float i01 = p01 * w01, i02 = p02 * w02;
      av0 += i01 * v00 + i02 * l_u[pp][0];
      av1 += i01 * v01 + i02 * l_u[pp][1];
      av2 += i01 * v02 + i02 * l_u[pp][2];
    }
  }
  const unsigned short* vbi = vbf_in + (size_t)i * F3;
  unsigned short* vbo = vbf_out + (size_t)i * F3;
  vbo[f] = f2bf(bf2f(vbi[f]) + av0);
  vbo[FDIM + f] = f2bf(bf2f(vbi[FDIM + f]) + av1);
  vbo[2 * FDIM + f] = f2bf(bf2f(vbi[2 * FDIM + f]) + av2);
  s[(size_t)i * FDIM + f] += acc_s;
}

// ---------------- update block via MFMA (v is bf16-only) ----------------
__global__ __launch_bounds__(256) void upd_mfma_kernel(
    float* __restrict__ s, unsigned short* __restrict__ vbf,
    const unsigned short* __restrict__ pU, const unsigned short* __restrict__ pV,
    const unsigned short* __restrict__ pW1, const float* __restrict__ b1,
    const unsigned short* __restrict__ pW2, const float* __restrict__ b2) {
  __shared__ bf16x8 vAf[3 * 4 * 64];
  __shared__ bf16x8 catA[8 * 64];
  __shared__ bf16x8 hA[4 * 64];
  int a0 = blockIdx.x * 16;
  int t = threadIdx.x;
  int lane = t & 63, w = t >> 6;
  {
    int l = t & 63, kb = (t >> 6) & 3;
    int m = l & 15, q = l >> 4;
#pragma unroll
    for (int rt = 0; rt < 3; rt++) {
      vAf[(rt * 4 + kb) * 64 + l] =
          *(const bf16x8*)(vbf + (size_t)(a0 + m) * F3 + rt * FDIM + kb * 32 + q * 8);
    }
    const float* sp = s + (size_t)(a0 + m) * FDIM + kb * 32 + q * 8;
    bf16x8 c;
#pragma unroll
    for (int j = 0; j < 8; j++) c[j] = (short)f2bf(sp[j]);
    catA[kb * 64 + l] = c;
  }
  __syncthreads();
  f32x4 accU[3][2], accV[3][2];
#pragma unroll
  for (int rt = 0; rt < 3; rt++)
#pragma unroll
    for (int t2 = 0; t2 < 2; t2++)
#pragma unroll
      for (int r = 0; r < 4; r++) { accU[rt][t2][r] = 0.0f; accV[rt][t2][r] = 0.0f; }
  const bf16x8* Uf = (const bf16x8*)pU;
  const bf16x8* Vf = (const bf16x8*)pV;
#pragma unroll
  for (int kb = 0; kb < 4; kb++) {
    bf16x8 bu[2], bv[2];
#pragma unroll
    for (int t2 = 0; t2 < 2; t2++) {
      bu[t2] = Uf[(kb * 8 + 2 * w + t2) * 64 + lane];
      bv[t2] = Vf[(kb * 8 + 2 * w + t2) * 64 + lane];
    }
#pragma unroll
    for (int rt = 0; rt < 3; rt++) {
      bf16x8 a = vAf[(rt * 4 + kb) * 64 + lane];
#pragma unroll
      for (int t2 = 0; t2 < 2; t2++) {
        accU[rt][t2] = __builtin_amdgcn_mfma_f32_16x16x32_bf16(a, bu[t2], accU[rt][t2], 0, 0, 0);
        accV[rt][t2] = __builtin_amdgcn_mfma_f32_16x16x32_bf16(a, bv[t2], accV[rt][t2], 0, 0, 0);
      }
    }
  }
  short* cs = (short*)catA;
#pragma unroll
  for (int t2 = 0; t2 < 2; t2++) {
    int g = w * 32 + t2 * 16 + (lane & 15);
    int k = 128 + g;
    int kb = k >> 5, q = (k >> 3) & 3, j = k & 7;
#pragma unroll
    for (int r = 0; r < 4; r++) {
      int m = (lane >> 4) * 4 + r;
      float x0 = accV[0][t2][r], x1 = accV[1][t2][r], x2 = accV[2][t2][r];
      cs[(kb * 64 + q * 16 + m) * 8 + j] = (short)f2bf(sqrtf(x0 * x0 + x1 * x1 + x2 * x2 + EPS_F));
    }
  }
  __syncthreads();
  f32x4 accH[2];
#pragma unroll
  for (int t2 = 0; t2 < 2; t2++)
#pragma unroll
    for (int r = 0; r < 4; r++) accH[t2][r] = 0.0f;
  const bf16x8* W1f = (const bf16x8*)pW1;
#pragma unroll
  for (int kb = 0; kb < 8; kb++) {
    bf16x8 a = catA[kb * 64 + lane];
#pragma unroll
    for (int t2 = 0; t2 < 2; t2++) {
      bf16x8 b = W1f[(kb * 8 + 2 * w + t2) * 64 + lane];
      accH[t2] = __builtin_amdgcn_mfma_f32_16x16x32_bf16(a, b, accH[t2], 0, 0, 0);
    }
  }
  short* hs = (short*)hA;
#pragma unroll
  for (int t2 = 0; t2 < 2; t2++) {
    int n = w * 32 + t2 * 16 + (lane & 15);
    int kb = n >> 5, q = (n >> 3) & 3, j = n & 7;
    float bias = b1[n];
#pragma unroll
    for (int r = 0; r < 4; r++) {
      int m = (lane >> 4) * 4 + r;
      hs[(kb * 64 + q * 16 + m) * 8 + j] = (short)f2bf(silu_f(accH[t2][r] + bias));
    }
  }
  __syncthreads();
  f32x4 accA[3][2];
#pragma unroll
  for (int c3 = 0; c3 < 3; c3++)
#pragma unroll
    for (int t2 = 0; t2 < 2; t2++)
#pragma unroll
      for (int r = 0; r < 4; r++) accA[c3][t2][r] = 0.0f;
  const bf16x8* W2f = (const bf16x8*)pW2;
#pragma unroll
  for (int kb = 0; kb < 4; kb++) {
    bf16x8 a = hA[kb * 64 + lane];
#pragma unroll
    for (int c3 = 0; c3 < 3; c3++)
#pragma unroll
      for (int t2 = 0; t2 < 2; t2++) {
        bf16x8 b = W2f[(kb * 24 + c3 * 8 + 2 * w + t2) * 64 + lane];
        accA[c3][t2] = __builtin_amdgcn_mfma_f32_16x16x32_bf16(a, b, accA[c3][t2], 0, 0, 0);
      }
  }
#pragma unroll
  for (int t2 = 0; t2 < 2; t2++) {
    int g = w * 32 + t2 * 16 + (lane & 15);
    float bb0 = b2[g], bb1 = b2[FDIM + g], bb2 = b2[2 * FDIM + g];
#pragma unroll
    for (int r = 0; r < 4; r++) {
      int m = (lane >> 4) * 4 + r;
      int n = a0 + m;
      float a0v = accA[0][t2][r] + bb0;
      float a1v = accA[1][t2][r] + bb1;
      float a2v = accA[2][t2][r] + bb2;
      float dot = accU[0][t2][r] * accV[0][t2][r] + accU[1][t2][r] * accV[1][t2][r] +
                  accU[2][t2][r] * accV[2][t2][r];
      s[(size_t)n * FDIM + g] += a1v * dot + a2v;
#pragma unroll
      for (int c = 0; c < 3; c++) {
        size_t ix = (size_t)n * F3 + c * FDIM + g;
        vbf[ix] = f2bf(bf2f(vbf[ix]) + a0v * accU[c][t2][r]);
      }
    }
  }
}

// ---------------- readout via MFMA ----------------
__global__ __launch_bounds__(256) void readout_mfma_kernel(
    const float* __restrict__ s, const unsigned short* __restrict__ pW1,
    const float* __restrict__ b1, const float* __restrict__ W2, const float* __restrict__ b2,
    const int* __restrict__ mol_idx, float* __restrict__ out) {
  __shared__ bf16x8 sA[4 * 64];
  __shared__ float red[4][16];
  int a0 = blockIdx.x * 16;
  int t = threadIdx.x;
  int lane = t & 63, w = t >> 6;
  {
    int kb = t >> 6, l = t & 63;
    int m = l & 15, q = l >> 4;
    const float* sp = s + (size_t)(a0 + m) * FDIM + kb * 32 + q * 8;
    bf16x8 c;
#pragma unroll
    for (int j = 0; j < 8; j++) c[j] = (short)f2bf(sp[j]);
    sA[kb * 64 + l] = c;
  }
  __syncthreads();
  f32x4 acc;
#pragma unroll
  for (int r = 0; r < 4; r++) acc[r] = 0.0f;
  const bf16x8* W1f = (const bf16x8*)pW1;
#pragma unroll
  for (int kb = 0; kb < 4; kb++) {
    bf16x8 a = sA[kb * 64 + lane];
    bf16x8 b = W1f[(kb * 4 + w) * 64 + lane];
    acc = __builtin_amdgcn_mfma_f32_16x16x32_bf16(a, b, acc, 0, 0, 0);
  }
  int col = w * 16 + (lane & 15);
  float bias = b1[col], w2v = W2[col];
  float val[4];
#pragma unroll
  for (int r = 0; r < 4; r++) val[r] = silu_f(acc[r] + bias) * w2v;
#pragma unroll
  for (int off = 1; off < 16; off <<= 1)
#pragma unroll
    for (int r = 0; r < 4; r++) val[r] += __shfl_xor(val[r], off, 64);
  if ((lane & 15) == 0) {
#pragma unroll
    for (int r = 0; r < 4; r++) red[w][(lane >> 4) * 4 + r] = val[r];
  }
  __syncthreads();
  if (t < 16) {
    float sum = red[0][t] + red[1][t] + red[2][t] + red[3][t] + b2[0];
    atomicAdd(&out[mol_idx[a0 + t]], sum);
  }
}

extern "C" void kernel_launch(void* const* d_in, const int* in_sizes, int n_in,
                              void* d_out, int out_size, void* d_ws, size_t ws_size,
                              hipStream_t stream) {
  const float* xyz = (const float*)d_in[0];
  const int* z = (const int*)d_in[1];
  const int* nbrs = (const int*)d_in[2];
  const int* mol = (const int*)d_in[3];
  const float* emb = (const float*)d_in[4];
  const float* msgW1 = (const float*)d_in[5];
  const float* msgb1 = (const float*)d_in[6];
  const float* msgW2 = (const float*)d_in[7];
  const float* msgb2 = (const float*)d_in[8];
  const float* distW = (const float*)d_in[9];
  const float* distb = (const float*)d_in[10];
  const float* updU = (const float*)d_in[11];
  const float* updV = (const float*)d_in[12];
  const float* updW1 = (const float*)d_in[13];
  const float* updb1 = (const float*)d_in[14];
  const float* updW2 = (const float*)d_in[15];
  const float* updb2 = (const float*)d_in[16];
  const float* rW1 = (const float*)d_in[17];
  const float* rb1 = (const float*)d_in[18];
  const float* rW2 = (const float*)d_in[19];
  const float* rb2 = (const float*)d_in[20];

  float* ws = (float*)d_ws;
  float* s = ws;      ws += (size_t)NA * FDIM;
  float* rbfc = ws;   ws += (size_t)NE * NRBF;
  float* fcut = ws;   ws += (size_t)NE;
  float* unitv = ws;  ws += (size_t)NE * 3;
  int* deg = (int*)ws;
  int* slot_e = deg + NA;
  int* slot_j = slot_e + NA * CAP;
  unsigned short* pk = (unsigned short*)(((uintptr_t)(slot_j + NA * CAP) + 15) & ~(uintptr_t)15);
  unsigned short* pMsgW1 = pk;                       // 49152
  unsigned short* pMsgW2 = pMsgW1 + 49152;           // 147456
  unsigned short* pUpdU  = pMsgW2 + 147456;          // 49152
  unsigned short* pUpdV  = pUpdU + 49152;            // 49152
  unsigned short* pUpdW1 = pUpdV + 49152;            // 98304
  unsigned short* pUpdW2 = pUpdW1 + 98304;           // 147456
  unsigned short* pRW1   = pUpdW2 + 147456;          // 8192
  unsigned short* pDW    = pRW1 + 8192;              // 3*12288
  unsigned short* phi_bf = (unsigned short*)(((uintptr_t)(pDW + 36864) + 15) & ~(uintptr_t)15);
  unsigned short* vbfA   = phi_bf + (size_t)NA * F3;
  unsigned short* vbfB   = vbfA + (size_t)NA * F3;

  hipMemsetAsync(deg, 0, NA * sizeof(int), stream);
  hipMemsetAsync(d_out, 0, NMOLS * sizeof(float), stream);

  pack_all_kernel<<<(585728 + 255) / 256, 256, 0, stream>>>(
      msgW1, msgW2, updU, updV, updW1, updW2, rW1, distW, distb, pMsgW1);
  geom_build_kernel<<<NE / 256, 256, 0, stream>>>(xyz, nbrs, unitv, rbfc, fcut,
                                                  deg, slot_e, slot_j);
  init_kernel<<<(NA * F3 + 255) / 256, 256, 0, stream>>>(emb, z, s, vbfA);

  unsigned short* vbfin = vbfA;
  unsigned short* vbfout = vbfB;
  for (int l = 0; l < NLAYERS; l++) {
    msg_mfma_kernel<<<NA / 16, 256, 0, stream>>>(
        s, pMsgW1 + (size_t)l * 16384, msgb1 + (size_t)l * FDIM,
        pMsgW2 + (size_t)l * 49152, msgb2 + (size_t)l * F3, phi_bf);
    edge_kernel<<<NA, 128, 0, stream>>>(phi_bf, vbfin, vbfout, s,
                                        pDW + (size_t)l * 12288,
                                        deg, slot_e, slot_j, rbfc, fcut, unitv);
    upd_mfma_kernel<<<NA / 16, 256, 0, stream>>>(
        s, vbfout, pUpdU + (size_t)l * 16384, pUpdV + (size_t)l * 16384,
        pUpdW1 + (size_t)l * 32768, updb1 + (size_t)l * FDIM,
        pUpdW2 + (size_t)l * 49152, updb2 + (size_t)l * F3);
    unsigned short* tb = vbfin; vbfin = vbfout; vbfout = tb;
  }
  readout_mfma_kernel<<<NA / 16, 256, 0, stream>>>(s, pRW1, rb1, rW2, rb2, mol, (float*)d_out);
}